// Round 10
// baseline (742.335 us; speedup 1.0000x reference)
//
#include <hip/hip_runtime.h>

// Problem constants
#define NB    128
#define NC    256
#define NPOS  196
#define NHEAD 8
#define NAG   49
#define YSTR  150528      // 768*196 per-batch y floats
#define VOFF  50176       // v_raw offset inside y (256*196)
#define QOFF  100352      // q_raw offset inside y (512*196)
#define SCL   0.17677669529663687f   // 32^-0.5

// Workspace layout (floats). Total = 38,885,440 floats = 155.5 MB.
#define WS_Y    0u
#define WS_V5   19267584u
#define WS_AT   25690112u
#define WS_ATK  27295744u
#define WS_CHG  28901376u   // avg -> overwritten in-place by chg (per-b partition)
#define WS_CMAP 28934144u
#define WS_PBT  28966912u
#define WS_AB   29043744u
#define WS_X1S  29120576u
#define WS_AGV  29153344u
#define WS_XO   30758976u
#define WS_WT   37181504u
#define WS_CWT  37247040u   // Wh: 1.6M ushort (fp16 conv5 weights, [tap][co][ci]) -> ends 38066240
#define WS_MX   38066240u   // [128][256] channel max (spare tail)
#define WS_MK   38099008u   // [128][196] spatial mask (spare tail; ends 38124096 < total)

typedef __attribute__((ext_vector_type(8))) _Float16 half8;
typedef __attribute__((ext_vector_type(8))) short short8;
typedef __attribute__((ext_vector_type(4))) short short4v;
typedef __attribute__((ext_vector_type(4))) float f32x4;
typedef unsigned short ushort_t;
typedef unsigned int uint_t;

__device__ __forceinline__ float sigmoidf_(float x){ return 1.0f/(1.0f+__expf(-x)); }

__device__ __forceinline__ ushort_t f2h(float x){
  _Float16 h = (_Float16)x; return __builtin_bit_cast(ushort_t, h);
}
__device__ __forceinline__ float h2f(ushort_t u){
  return (float)__builtin_bit_cast(_Float16, u);
}

// bilinear upsample 7x7 -> 14x14 sample at (i,j), matching reference grid()
__device__ __forceinline__ float bilin7(const float* __restrict__ src, int i, int j){
  float pi = fmaxf(0.5f*(float)i - 0.25f, 0.f);
  int i0 = (int)pi; if (i0 > 6) i0 = 6;
  int i1 = i0 + 1;  if (i1 > 6) i1 = 6;
  float li = pi - (float)i0;
  float pj = fmaxf(0.5f*(float)j - 0.25f, 0.f);
  int j0 = (int)pj; if (j0 > 6) j0 = 6;
  int j1 = j0 + 1;  if (j1 > 6) j1 = 6;
  float lj = pj - (float)j0;
  float v00 = src[i0*7+j0], v01 = src[i0*7+j1];
  float v10 = src[i1*7+j0], v11 = src[i1*7+j1];
  float t0 = v00*(1.f-lj) + v01*lj;
  float t1 = v10*(1.f-lj) + v11*lj;
  return t0*(1.f-li) + t1*li;
}

// 5x5 conv over a zero-padded [18][20] plane, producing one 14-wide output row r.
__device__ __forceinline__ void conv5x5_row(const float* __restrict__ plane, int r,
                                            const float* __restrict__ w25, float* acc14){
  #pragma unroll
  for (int di = 0; di < 5; ++di){
    const float4* pr = (const float4*)(plane + (r+di)*20);
    float4 p0 = pr[0], p1 = pr[1], p2 = pr[2], p3 = pr[3], p4 = pr[4];
    float row[20] = {p0.x,p0.y,p0.z,p0.w, p1.x,p1.y,p1.z,p1.w, p2.x,p2.y,p2.z,p2.w,
                     p3.x,p3.y,p3.z,p3.w, p4.x,p4.y,p4.z,p4.w};
    #pragma unroll
    for (int dj = 0; dj < 5; ++dj){
      float w = w25[di*5+dj];
      #pragma unroll
      for (int j = 0; j < 14; ++j) acc14[j] = fmaf(row[j+dj], w, acc14[j]);
    }
  }
}

// ---------- prep kernels ----------
// merged pb+ab: blocks [0,301) -> PBT, [301,602) -> AB
__global__ void k_pbab(const float* __restrict__ an, const float* __restrict__ ah,
                       const float* __restrict__ aw, const float* __restrict__ na,
                       const float* __restrict__ ha, const float* __restrict__ wa,
                       float* __restrict__ PBT, float* __restrict__ AB){
  int bid = blockIdx.x;
  int which = (bid >= 301);
  int t = (which ? bid - 301 : bid)*256 + threadIdx.x;
  if (t >= NHEAD*NPOS*NAG) return;
  int a = t % NAG;
  int r = t / NAG;
  int n = r % NPOS;
  int h = r / NPOS;
  int i = n/14, j = n - (n/14)*14;
  if (!which){
    float v = bilin7(an + ((size_t)h*NAG + a)*49, i, j);
    v += ah[((size_t)h*NAG + a)*14 + i] + aw[((size_t)h*NAG + a)*14 + j];
    PBT[t] = v;   // [h][n][a]
  } else {
    float v = bilin7(na + ((size_t)h*NAG + a)*49, i, j);
    v += ha[((size_t)h*14 + i)*NAG + a] + wa[((size_t)h*14 + j)*NAG + a];
    AB[t] = v;    // [h][n][a]
  }
}

// merged weight prep: blocks [0,800) -> conv5 fp16 weights (8 elems/thread),
// blocks [800,1056) -> proj_w transpose.
__global__ void k_wprep(const float* __restrict__ cw, ushort_t* __restrict__ Wh,
                        const float* __restrict__ pw, float* __restrict__ WT){
  int bid = blockIdx.x;
  if (bid < 800){
    int base = (bid*256 + threadIdx.x)*8;       // < 1638400; 8 | 256 so r uniform
    int r   = base >> 8;
    int co  = r & 255;
    int tap = r >> 8;
    int ci0 = base & 255;
    const float* srcb = cw + (size_t)co*6400 + (size_t)ci0*25 + tap;
    short8 o;
    #pragma unroll
    for (int e = 0; e < 8; ++e) o[e] = (short)f2h(srcb[e*25]);
    *(short8*)(Wh + base) = o;                  // Wh[tap][co][ci]
  } else {
    int t = (bid - 800)*256 + threadIdx.x;      // < 65536
    int k = t >> 8, c = t & 255;
    WT[t] = pw[c*256 + k];                      // WT[k][c] = proj_w[c][k]
  }
}

// ---------- lka depthwise-ish conv (groups=256, 3 outputs per input channel) ----------
__global__ __launch_bounds__(256) void k_lka(const float* __restrict__ x, const float* __restrict__ lw,
                                             const float* __restrict__ lb, float* __restrict__ Y){
  int b = blockIdx.x >> 3, gb = blockIdx.x & 7;
  int g0 = gb*32;                               // input channels [g0,g0+32)
  __shared__ __align__(16) float pl[32*360];    // [ch][18*20] padded planes
  int tid = threadIdx.x;
  for (int t = tid; t < 32*360; t += 256) pl[t] = 0.f;
  __syncthreads();
  for (int t = tid; t < 32*196; t += 256){
    int gl = t & 31, s = t >> 5;
    int i = s/14, j = s - i*14;
    pl[gl*360 + (i+2)*20 + j + 2] = x[((size_t)b*196 + s)*256 + g0 + gl];
  }
  __syncthreads();
  for (int t = tid; t < 96*14; t += 256){
    int ocl = t/14, r = t - ocl*14;
    int o  = g0*3 + ocl;          // output channel; uses input channel o/3
    int gl = ocl/3;
    float w25[25];
    #pragma unroll
    for (int u = 0; u < 25; ++u) w25[u] = lw[o*25 + u];
    float acc[14];
    float bv = lb[o];
    #pragma unroll
    for (int j = 0; j < 14; ++j) acc[j] = bv;
    conv5x5_row(&pl[gl*360], r, w25, acc);
    float* dst = Y + ((size_t)b*768 + o)*196 + r*14;
    #pragma unroll
    for (int j = 0; j < 14; ++j) dst[j] = acc[j];
  }
}

// ---------- conv5 via fp16 MFMA implicit GEMM, W double-buffered (round-7 winner) ----------
__global__ __launch_bounds__(256, 2) void k_conv5(const float* __restrict__ Y,
    const ushort_t* __restrict__ Wh, const float* __restrict__ cb, float* __restrict__ V5){
  int b = blockIdx.x >> 2, cog = blockIdx.x & 3;
  int co0 = cog*64;
  __shared__ __align__(16) ushort_t Pt[360*40];       // fp16 A: [pos][4 chunks of 8ci + pad]
  __shared__ __align__(16) ushort_t Wsm[2*5*64*40];   // fp16 B, double-buffered
  float* T = (float*)Wsm;                             // epilogue transpose (buffer 0)
  int tid  = threadIdx.x;
  int lane = tid & 63, wv = tid >> 6;
  int mrow = lane & 15, quad = lane >> 4;

  for (int t = tid; t < 7200; t += 256) ((uint_t*)Pt)[t] = 0;

  int prow[4];
  #pragma unroll
  for (int mt = 0; mt < 4; ++mt){
    int s = wv*64 + mt*16 + mrow;
    int p0 = 0;
    if (s < 196){ int i = s/14, j = s - i*14; p0 = i*20 + j; }
    prow[mt] = p0;
  }

  f32x4 acc[4][4];
  #pragma unroll
  for (int mt = 0; mt < 4; ++mt)
    #pragma unroll
    for (int nt = 0; nt < 4; ++nt) acc[mt][nt] = (f32x4){0.f,0.f,0.f,0.f};

  const float* src = Y + (size_t)b*YSTR + VOFF;   // v_raw [ci][s]
  int wco = tid >> 2, wpart = tid & 3;            // W-staging roles
  const ushort_t* wbase = Wh + ((size_t)(co0 + wco))*256 + wpart*8;  // + tap*65536 + cc*32

  short8 wreg[5];
  #pragma unroll
  for (int tp = 0; tp < 5; ++tp)
    wreg[tp] = *(const short8*)(wbase + (size_t)tp*65536);

  #pragma unroll 1
  for (int cc = 0; cc < 8; ++cc){
    __syncthreads();              // Pt free to overwrite (prev cc compute done)
    for (int t = tid; t < 784; t += 256){
      int pos = t >> 2, ch = t & 3;
      int i = pos/14, j = pos - i*14;
      int p = (i+2)*20 + j + 2;
      const float* s0 = src + (size_t)(cc*32 + ch*8)*196 + pos;
      short8 pk;
      #pragma unroll
      for (int e = 0; e < 4; ++e){
        float v0 = s0[(2*e)*196];
        float v1 = s0[(2*e+1)*196];
        pk[2*e]   = (short)f2h(v0);
        pk[2*e+1] = (short)f2h(v1);
      }
      *(short8*)&Pt[p*40 + ch*8] = pk;
    }
    #pragma unroll 1
    for (int di = 0; di < 5; ++di){
      int u = cc*5 + di;
      ushort_t* wbuf = Wsm + (u & 1)*12800;
      #pragma unroll
      for (int tp = 0; tp < 5; ++tp)
        *(short8*)&wbuf[(tp*64 + wco)*40 + wpart*8] = wreg[tp];
      if (u < 39){
        int di1 = di + 1, cc1 = cc;
        if (di1 == 5){ di1 = 0; ++cc1; }
        #pragma unroll
        for (int tp = 0; tp < 5; ++tp)
          wreg[tp] = *(const short8*)(wbase + (size_t)(di1*5 + tp)*65536 + cc1*32);
      }
      __syncthreads();      // fences A writes (di=0) and this step's W writes
      #pragma unroll
      for (int dj = 0; dj < 5; ++dj){
        half8 a[4], bb[4];
        #pragma unroll
        for (int nt = 0; nt < 4; ++nt){
          int co = nt*16 + mrow;
          bb[nt] = *(const half8*)&wbuf[(dj*64 + co)*40 + quad*8];
        }
        #pragma unroll
        for (int mt = 0; mt < 4; ++mt){
          int p = prow[mt] + di*20 + dj;
          a[mt] = *(const half8*)&Pt[p*40 + quad*8];
        }
        #pragma unroll
        for (int mt = 0; mt < 4; ++mt)
          #pragma unroll
          for (int nt = 0; nt < 4; ++nt)
            acc[mt][nt] = __builtin_amdgcn_mfma_f32_16x16x32_f16(a[mt], bb[nt], acc[mt][nt], 0, 0, 0);
      }
    }
  }

  // epilogue: transpose through LDS (T = Wsm buffer 0), stores into scrambled v5
  #pragma unroll
  for (int hf = 0; hf < 2; ++hf){
    __syncthreads();
    #pragma unroll
    for (int ntl = 0; ntl < 2; ++ntl){
      int nt = hf*2 + ntl;
      int col = ntl*16 + mrow;            // co local within half (0..31)
      #pragma unroll
      for (int mt = 0; mt < 4; ++mt){
        int sbase = wv*64 + mt*16 + quad*4;
        #pragma unroll
        for (int r = 0; r < 4; ++r){
          int s = sbase + r;
          if (s < 196) T[col*200 + s] = acc[mt][nt][r];
        }
      }
    }
    __syncthreads();
    for (int t = tid; t < 6272; t += 256){
      int cl = t / 196;                   // co local 0..31
      int f = (co0 + hf*32)*196 + t;
      float val = T[t + cl*4] + cb[co0 + hf*32 + cl];
      V5[(size_t)b*50176 + (size_t)(f & 255)*196 + (f >> 8)] = val;
    }
  }
}

// ---------- agent token pooling (256 blocks: channel-half x agent-half split) ----------
__global__ __launch_bounds__(256) void k_pool(const float* __restrict__ Y, float* __restrict__ AT, float* __restrict__ ATK){
  int b = blockIdx.x >> 1, half = blockIdx.x & 1;
  int c = (threadIdx.x & 127) + half*128;
  int a0 = (threadIdx.x >> 7) ? 25 : 0;
  int a1 = (threadIdx.x >> 7) ? 49 : 25;
  const float* qp = Y + ((size_t)b*768 + 512 + c)*196;
  const float* kp = Y + ((size_t)b*768 + c)*196;
  for (int a = a0; a < a1; ++a){
    int p1 = a/7, p2 = a - p1*7;
    int s = p1*28 + p2*2;
    float q0 = qp[s], q1 = qp[s+1], q2 = qp[s+14], q3 = qp[s+15];
    AT[((size_t)b*49 + a)*256 + c] = 0.25f*(q0+q1+q2+q3);
    float k0 = kp[s], k1 = kp[s+1], k2 = kp[s+14], k3 = kp[s+15];
    ATK[((size_t)b*49 + a)*256 + c] = fmaxf(fmaxf(k0,k1), fmaxf(k2,k3));
  }
}

// ---------- cbam stage A: per-channel stats, high parallelism (1024 blocks) ----------
// 32 channels per block (8 iters/wave), coalesced float4 + 64-lane shuffle reduce.
__global__ __launch_bounds__(256) void k_cbam_a2(const float* __restrict__ V5,
    float* __restrict__ AVG, float* __restrict__ MX){
  int b = blockIdx.x >> 3, oct = blockIdx.x & 7;
  int tid = threadIdx.x, wv = tid >> 6, lane = tid & 63;
  const float* v5b = V5 + (size_t)b*50176;
  #pragma unroll
  for (int i = 0; i < 8; ++i){
    int c = oct*32 + i*4 + wv;
    float s, m;
    if (lane < 49){
      float4 v = *(const float4*)(v5b + c*196 + lane*4);
      s = v.x + v.y + v.z + v.w;
      m = fmaxf(fmaxf(v.x, v.y), fmaxf(v.z, v.w));
    } else { s = 0.f; m = -1e30f; }
    #pragma unroll
    for (int off = 1; off < 64; off <<= 1){
      s += __shfl_xor(s, off);
      m = fmaxf(m, __shfl_xor(m, off));
    }
    if (lane == 0){
      AVG[b*256 + c] = s*(1.0f/196.0f);
      MX[b*256 + c]  = m;
    }
  }
}

// ---------- cbam stage B: MLP -> chg, spatial mask -> MK. V5 NOT modified ----------
__global__ __launch_bounds__(512) void k_cbam_b2(const float* __restrict__ V5,
    float* __restrict__ AVGCHG, const float* __restrict__ MX,
    const float* __restrict__ caa1w, const float* __restrict__ caa1b,
    const float* __restrict__ caa2w, const float* __restrict__ caa2b,
    const float* __restrict__ cam1w, const float* __restrict__ cam1b,
    const float* __restrict__ cam2w, const float* __restrict__ cam2b,
    const float* __restrict__ saw, const float* __restrict__ sab,
    float* __restrict__ MK){
  int b = blockIdx.x;
  __shared__ float avg[256], mx[256], t1[16], t2[16], chg[256];
  __shared__ float sp[2][196], sx[2][196];
  __shared__ float mp[22*22], xp[22*22];
  int tid = threadIdx.x;
  if (tid < 256) avg[tid] = AVGCHG[b*256 + tid];
  else           mx[tid - 256] = MX[b*256 + tid - 256];
  for (int t = tid; t < 484; t += 512){ mp[t] = 0.f; xp[t] = 0.f; }
  __syncthreads();

  if (tid < 16){
    float a1 = caa1b[tid], a2 = cam1b[tid];
    #pragma unroll 4
    for (int k = 0; k < 256; ++k){
      a1 = fmaf(caa1w[(tid*256 + k)*9 + 4], avg[k], a1);   // 3x3 center tap
      a2 = fmaf(cam1w[tid*256 + k], mx[k], a2);            // 1x1
    }
    t1[tid] = fmaxf(a1, 0.f);
    t2[tid] = fmaxf(a2, 0.f);
  }
  __syncthreads();
  if (tid < 256){
    float y1 = caa2b[tid], y2 = cam2b[tid];
    #pragma unroll
    for (int k = 0; k < 16; ++k){
      y1 = fmaf(caa2w[(tid*16 + k)*9 + 4], t1[k], y1);
      y2 = fmaf(cam2w[tid*16 + k], t2[k], y2);
    }
    float g = sigmoidf_(sigmoidf_(y1) + sigmoidf_(y2));
    chg[tid] = g;
    AVGCHG[b*256 + tid] = g;            // chg overwrites avg (avg already in LDS)
  }
  __syncthreads();

  // spatial mean/max over channels, split across 2 half-channel groups
  {
    int g = tid >> 8, pos = tid & 255;
    if (pos < 196){
      const float* vb = V5 + (size_t)b*50176 + pos;
      float s = 0.f, m = -1e30f;
      for (int c = g*128; c < g*128 + 128; ++c){
        float v = chg[c] * vb[c*196];
        s += v; m = fmaxf(m, v);
      }
      sp[g][pos] = s; sx[g][pos] = m;
    }
  }
  __syncthreads();
  if (tid < 196){
    int i = tid/14, j = tid - i*14;
    mp[(i+4)*22 + j+4] = (sp[0][tid] + sp[1][tid])*(1.f/256.f);
    xp[(i+4)*22 + j+4] = fmaxf(sx[0][tid], sx[1][tid]);
  }
  __syncthreads();
  if (tid < 196){
    int i = tid/14, j = tid - i*14;
    float acc = sab[0];
    for (int di = 0; di < 9; ++di){
      #pragma unroll
      for (int dj = 0; dj < 9; ++dj){
        acc = fmaf(mp[(i+di)*22 + j+dj], saw[di*9+dj], acc);
        acc = fmaf(xp[(i+di)*22 + j+dj], saw[81 + di*9+dj], acc);
      }
    }
    MK[(size_t)b*196 + tid] = sigmoidf_(acc);
  }
}

// ---------- big NxN attention via MFMA, 3-segment version (round-6) ----------
__global__ __launch_bounds__(512, 4) void k_attn3(const float* __restrict__ Y,
    const float* __restrict__ rpbt, float* __restrict__ X1S){
  int b = blockIdx.x >> 3, h = blockIdx.x & 7;
  __shared__ __align__(16) ushort_t Qh[208*32];    // fp16 q*SCL rows, chunk-swizzled
  __shared__ __align__(16) ushort_t Kh[208*32];    // fp16 k rows, chunk-swizzled
  __shared__ __align__(16) ushort_t E[80*208];     // fp16 exp-scores [n-local][j]
  __shared__ float rp[736];
  __shared__ int   rpo[208];
  __shared__ float pl2[80][2];                     // lsum halves per row
  __shared__ float invl[80];
  __shared__ float wj[208];
  __shared__ float wpart[8][208];
  __shared__ float xpart[16][32];
  int tid = threadIdx.x, wv = tid >> 6, lane = tid & 63;
  int mrow = lane & 15, quad = lane >> 4;
  int sw8 = ((quad ^ ((mrow >> 1) & 3)) << 3);     // 64B-row read swizzle
  const float* yb = Y + (size_t)b*YSTR;

  for (int t = tid; t < 736; t += 512) rp[t] = (t < 729) ? rpbt[t*8 + h] : 0.f;
  for (int j = tid; j < 208; j += 512){
    int jc = (j < 196) ? j : 195;
    int rj = jc/14;
    rpo[j] = rj*27 + (jc - rj*14);
    wj[j] = 0.f;
  }
  for (int t = tid; t < 384; t += 512){            // zero rows 196..207 of Qh/Kh
    int arr = t >= 192; int u = t - arr*192;
    ((uint_t*)(arr ? Kh : Qh))[3136 + u] = 0;
  }
  for (int t = tid; t < 3136; t += 512){
    int n = t >> 4, w = t & 15;
    int ws = (((w >> 2) ^ ((n >> 1) & 3)) << 2) | (w & 3);
    const float2 qv = *(const float2*)(yb + QOFF + (size_t)n*256 + h*32 + (w << 1));
    ((uint_t*)Qh)[n*16 + ws] = (uint_t)f2h(qv.x*SCL) | ((uint_t)f2h(qv.y*SCL) << 16);
    const float2 kv = *(const float2*)(yb + (size_t)n*256 + h*32 + (w << 1));
    ((uint_t*)Kh)[n*16 + ws] = (uint_t)f2h(kv.x) | ((uint_t)f2h(kv.y) << 16);
  }
  __syncthreads();

  int mt0 = (wv & 1) ? 7 : 0;
  int mt1 = (wv & 1) ? 13 : 7;

  #pragma unroll 1
  for (int seg = 0; seg < 3; ++seg){
    int base = (seg == 0) ? 0 : (seg == 1) ? 80 : 144;
    int ntl  = (seg == 0) ? 5 : 4;
    int segrows = ntl*16;
    int vrows = 196 - base; if (vrows > segrows) vrows = segrows;

    #pragma unroll 1
    for (int ncl = (wv >> 1); ncl < ntl; ncl += 4){
      int n = base + ncl*16 + mrow;
      half8 bfr = *(const half8*)&Qh[n*32 + sw8];
      int nclamp = (n < 196) ? n : 195;
      int rin = nclamp/14, cin = nclamp - rin*14;
      int bidxn = (rin + 13)*27 + (cin + 13);
      float lsum = 0.f;
      #pragma unroll 1
      for (int mt = mt0; mt < mt1; ++mt){
        half8 afr = *(const half8*)&Kh[(mt*16 + mrow)*32 + sw8];
        f32x4 c = (f32x4){0.f,0.f,0.f,0.f};
        c = __builtin_amdgcn_mfma_f32_16x16x32_f16(afr, bfr, c, 0, 0, 0);
        int j0 = mt*16 + quad*4;
        int4 ro = *(const int4*)&rpo[j0];
        short4v pk;
        #pragma unroll
        for (int r = 0; r < 4; ++r){
          int j = j0 + r;
          int roff = (r == 0) ? ro.x : (r == 1) ? ro.y : (r == 2) ? ro.z : ro.w;
          float e = (j < 196) ? __expf(c[r] + rp[bidxn - roff]) : 0.f;
          lsum += e;
          pk[r] = (short)f2h(e);
        }
        if (n < 196) *(short4v*)&E[(n - base)*208 + j0] = pk;
      }
      lsum += __shfl_xor(lsum, 16);
      lsum += __shfl_xor(lsum, 32);
      if (quad == 0) pl2[n - base][wv & 1] = lsum;
    }
    __syncthreads();
    for (int t = tid; t < vrows; t += 512) invl[t] = 1.f/(pl2[t][0] + pl2[t][1]);
    __syncthreads();

    {
      int j0 = lane*4;
      if (j0 < 208){
        float a0=0.f,a1=0.f,a2=0.f,a3=0.f;
        #pragma unroll 1
        for (int nl = wv; nl < vrows; nl += 8){
          float iv = invl[nl];
          short4v ev = *(const short4v*)&E[nl*208 + j0];
          a0 = fmaf(h2f((ushort_t)ev[0]), iv, a0);
          a1 = fmaf(h2f((ushort_t)ev[1]), iv, a1);
          a2 = fmaf(h2f((ushort_t)ev[2]), iv, a2);
          a3 = fmaf(h2f((ushort_t)ev[3]), iv, a3);
        }
        *(f32x4*)&wpart[wv][j0] = (f32x4){a0,a1,a2,a3};
      }
    }
    __syncthreads();
    for (int j = tid; j < 208; j += 512){
      float s = wj[j];
      #pragma unroll
      for (int g = 0; g < 8; ++g) s += wpart[g][j];
      wj[j] = s;
    }
    __syncthreads();   // wpart/E/pl2/invl free for next segment
  }

  {
    int d = tid & 31, g = tid >> 5;                // 16 groups x 13 j's
    float s = 0.f;
    #pragma unroll 1
    for (int u = 0; u < 13; ++u){
      int j = g*13 + u;
      s = fmaf(wj[j], yb[VOFF + (size_t)j*256 + h*32 + d], s);
    }
    xpart[g][d] = s;
  }
  __syncthreads();
  if (tid < 32){
    float s = 0.f;
    #pragma unroll
    for (int g2 = 0; g2 < 16; ++g2) s += xpart[g2][tid];
    X1S[(size_t)b*256 + h*32 + tid] = s*(1.f/196.f);
  }
}

// ---------- chan_inter on x1 mean -> sigmoid gate CMAP ----------
__global__ __launch_bounds__(256) void k_cinter(const float* __restrict__ X1S,
    const float* __restrict__ ci1w, const float* __restrict__ ci1b,
    const float* __restrict__ bng, const float* __restrict__ bnb,
    const float* __restrict__ ci2w, const float* __restrict__ ci2b, float* __restrict__ CMAP){
  int b = blockIdx.x, c = threadIdx.x;
  __shared__ float p[256], tt[16];
  p[c] = X1S[b*256 + c];
  __syncthreads();
  if (c < 16){
    float a = ci1b[c];
    #pragma unroll 4
    for (int k = 0; k < 256; ++k) a = fmaf(ci1w[(c*256+k)*25 + 12], p[k], a);  // 5x5 center
    const float invs = 0.9999950000375f;   // 1/sqrt(1+1e-5)
    tt[c] = fmaxf(fmaf(bng[c]*invs, a, bnb[c]), 0.f);
  }
  __syncthreads();
  float a = ci2b[c];
  #pragma unroll
  for (int k = 0; k < 16; ++k) a = fmaf(ci2w[(c*16+k)*25 + 12], tt[k], a);
  CMAP[b*256 + c] = sigmoidf_(a);
}

// ---------- agent_v via fp16 MFMA (round-9: gate fused into pass-0 V staging) ----------
__global__ __launch_bounds__(256) void k_agentv(const float* __restrict__ Y, const float* __restrict__ V5,
    const float* __restrict__ CHG, const float* __restrict__ MK,
    const float* __restrict__ AT, const float* __restrict__ ATK,
    const float* __restrict__ PBT, float* __restrict__ AGV){
  int b = blockIdx.x >> 3, h = blockIdx.x & 7;
  __shared__ __align__(16) ushort_t ST[64*232];   // exp-scores, [a][n pad 232]
  __shared__ __align__(16) ushort_t R[8704];      // staging region (17408 B)
  __shared__ float psum[4*64];
  __shared__ float inv0s[64], inv1s[64];
  __shared__ float mks[196];
  __shared__ float chgs[32];
  int tid = threadIdx.x, wv = tid >> 6, lane = tid & 63;
  int mrow = lane & 15, quad = lane >> 4;
  int sw8 = ((quad ^ ((mrow >> 1) & 3)) << 3);    // read-side chunk swizzle (rows = 16*t + mrow)
  const float* yb = Y + (size_t)b*YSTR;
  ushort_t* Kh = R;            // [208][32] fp16 rows (K or Q), chunk-swizzled
  ushort_t* Ah = R + 6656;     // [64][32] fp16 rows (AT or ATK), chunk-swizzled
  ushort_t* Vt = R;            // [32][232] fp16 rows (V1 or V)
  f32x4 out0[2], out1[2];

  // ---- one-time: gate tables + zero fills of ST cols 208..223 ----
  if (tid < 196) mks[tid] = MK[(size_t)b*196 + tid];
  if (tid >= 224) chgs[tid - 224] = CHG[(size_t)b*256 + h*32 + (tid - 224)];
  for (int t = tid; t < 512; t += 256){      // 64 rows x 16 cols /2 per uint
    int a = t >> 3, c2 = 208 + ((t & 7) << 1);
    *(uint_t*)&ST[a*232 + c2] = 0;
  }

  #pragma unroll 1
  for (int pass = 0; pass < 2; ++pass){
    // ---- stage rows (K|Q into Kh; AT|ATK into Ah), zero pads ----
    for (int t = tid; t < 192; t += 256) ((uint_t*)Kh)[3136 + t] = 0;   // rows 196-207
    for (int t = tid; t < 240; t += 256) ((uint_t*)Ah)[784 + t] = 0;    // rows 49-63
    {
      const float* rsrc = yb + (pass ? QOFF : 0) + h*32;
      for (int t = tid; t < 3136; t += 256){
        int n = t >> 4, w = t & 15;
        const float2 v = *(const float2*)(rsrc + (size_t)n*256 + (w << 1));
        int ws = (((w >> 2) ^ ((n >> 1) & 3)) << 2) | (w & 3);
        ((uint_t*)Kh)[n*16 + ws] = (uint_t)f2h(v.x) | ((uint_t)f2h(v.y) << 16);
      }
      const float* asrc = (pass ? ATK : AT) + (size_t)b*49*256 + h*32;
      for (int t = tid; t < 784; t += 256){
        int a = t >> 4, w = t & 15;
        const float2 v = *(const float2*)(asrc + (size_t)a*256 + (w << 1));
        int ws = (((w >> 2) ^ ((a >> 1) & 3)) << 2) | (w & 3);
        ((uint_t*)Ah)[a*16 + ws] = (uint_t)f2h(v.x) | ((uint_t)f2h(v.y) << 16);
      }
    }
    __syncthreads();
    // ---- logits: ntile = wv; 13 mtiles; exp(+pb) -> ST[a][n] ----
    {
      float lscl = pass ? 0.03125f : SCL;
      int ag = wv*16 + mrow;                 // agent (C col)
      half8 bfr = *(const half8*)&Ah[ag*32 + sw8];
      #pragma unroll 1
      for (int mt = 0; mt < 13; ++mt){
        half8 afr = *(const half8*)&Kh[(mt*16 + mrow)*32 + sw8];
        f32x4 c = (f32x4){0.f,0.f,0.f,0.f};
        c = __builtin_amdgcn_mfma_f32_16x16x32_f16(afr, bfr, c, 0, 0, 0);
        int n0 = mt*16 + quad*4;
        short4v pk;
        #pragma unroll
        for (int r = 0; r < 4; ++r){
          int n = n0 + r;
          float pb = PBT[((size_t)h*196 + n)*49 + ag];
          float e = (n < 196) ? __expf(fmaf(c[r], lscl, pb)) : 0.f;
          pk[r] = (short)f2h(e);
        }
        *(short4v*)&ST[ag*232 + n0] = pk;
      }
    }
    __syncthreads();
    // ---- denominators + stage V ----
    {
      int a = tid >> 2, q = tid & 3;
      float s = 0.f;
      #pragma unroll
      for (int u = 0; u < 7; ++u){
        short8 v8 = *(const short8*)&ST[a*232 + q*56 + u*8];
        #pragma unroll
        for (int e = 0; e < 8; ++e) s += h2f((ushort_t)v8[e]);
      }
      psum[q*64 + a] = s;
    }
    if (pass == 0){
      const float* vsrc = V5 + (size_t)b*50176 + h*32*196;   // [d][196] raw v5
      for (int t = tid; t < 3136; t += 256){
        int d = t / 98, np = t - (t/98)*98;
        const float2 v = *(const float2*)(vsrc + (size_t)d*196 + 2*np);
        float g = chgs[d];
        float a0 = (g*v.x)*mks[2*np];
        float a1 = (g*v.y)*mks[2*np + 1];
        *(uint_t*)&Vt[d*232 + 2*np] = (uint_t)f2h(a0) | ((uint_t)f2h(a1) << 16);
      }
    } else {
      const float* vsrc = yb + VOFF + h*32;                  // [n][256] flat view
      for (int t = tid; t < 3136; t += 256){
        int np = t >> 4, dp = t & 15;
        const float2 v = *(const float2*)(vsrc + (size_t)np*256 + (dp << 1));
        Vt[(2*dp)*232 + np]     = f2h(v.x);
        Vt[(2*dp + 1)*232 + np] = f2h(v.y);
      }
    }
    for (int t = tid; t < 448; t += 256){    // zero V cols 196..223
      int d = t / 14, c2 = 196 + 2*(t - (t/14)*14);
      *(uint_t*)&Vt[d*232 + c2] = 0;
    }
    __syncthreads();
    // ---- PV: mtile = wv (a rows); ntile 0..1 (d cols); 7 k-steps ----
    {
      f32x4* outp = pass ? out1 : out0;
      #pragma unroll
      for (int nt = 0; nt < 2; ++nt){
        f32x4 c = (f32x4){0.f,0.f,0.f,0.f};
        #pragma unroll
        for (int ks = 0; ks < 7; ++ks){
          half8 afr = *(const half8*)&ST[(wv*16 + mrow)*232 + ks*32 + quad*8];
          half8 bfr = *(const half8*)&Vt[(nt*16 + mrow)*232 + ks*32 + quad*8];
          c = __builtin_amdgcn_mfma_f32_16x16x32_f16(afr, bfr, c, 0, 0, 0);
        }
        outp[nt] = c;
      }
      if (tid < 64){
        float s = psum[tid] + psum[64+tid] + psum[128+tid] + psum[192+tid];
        float* invp = pass ? inv1s : inv0s;
        invp[tid] = 1.f / s;
      }
    }
    __syncthreads();   // ST/Vt free for next pass; inv visible
  }
  // ---- epilogue: combine + scatter ----
  #pragma unroll
  for (int nt = 0; nt < 2; ++nt){
    int d = nt*16 + mrow;
    #pragma unroll
    for (int r = 0; r < 4; ++r){
      int a = wv*16 + quad*4 + r;
      if (a < 49)
        AGV[(((size_t)(b*8 + h)*49) + a)*32 + d] = out0[nt][r]*inv0s[a] + out1[nt][r]*inv1s[a];
    }
  }
}

// ---------- xo1 via fp16 MFMA; store routed through LDS for coalesced float4 ----------
__global__ __launch_bounds__(256) void k_xo1(const float* __restrict__ Y,
    const float* __restrict__ AT, const float* __restrict__ ATK,
    const float* __restrict__ AB, const float* __restrict__ AGV, float* __restrict__ XO){
  int b = blockIdx.x >> 3, h = blockIdx.x & 7;
  __shared__ __align__(16) ushort_t ST[208*72];   // exp-scores [n][a pad 72]; reused as out-tile
  __shared__ __align__(16) ushort_t Kh[208*32];   // Q or K rows fp16, chunk-swizzled
  __shared__ __align__(16) ushort_t Ah[64*32];    // AT or ATK rows fp16, chunk-swizzled
  __shared__ __align__(16) ushort_t AGVt[32*64];  // AGV^T [d][a], chunk-swizzled
  __shared__ float invs[208];
  int tid = threadIdx.x, wv = tid >> 6, lane = tid & 63;
  int mrow = lane & 15, quad = lane >> 4;
  int sw8 = ((quad ^ ((mrow >> 1) & 3)) << 3);    // 64B-row read swizzle
  const float* yb = Y + (size_t)b*YSTR;
  f32x4 acc[4][2];
  #pragma unroll
  for (int i = 0; i < 4; ++i){
    acc[i][0] = (f32x4){0.f,0.f,0.f,0.f};
    acc[i][1] = (f32x4){0.f,0.f,0.f,0.f};
  }

  for (int t = tid; t < 1664; t += 256){
    int rw = t >> 3, c2 = 48 + ((t & 7) << 1);
    *(uint_t*)&ST[rw*72 + c2] = 0;
  }
  {
    const float* agvb = AGV + (size_t)(b*8 + h)*49*32;
    for (int t = tid; t < 2048; t += 256){
      int d = t >> 6, a = t & 63;
      int as = ((((a >> 3) ^ (d & 7)) & 7) << 3) | (a & 7);
      AGVt[d*64 + as] = (a < 49) ? f2h(agvb[a*32 + d]) : (ushort_t)0;
    }
  }

  #pragma unroll 1
  for (int pass = 0; pass < 2; ++pass){
    {
      const float* rsrc = yb + (pass ? 0 : QOFF) + h*32;
      for (int t = tid; t < 3136; t += 256){
        int n = t >> 4, w = t & 15;
        const float2 v = *(const float2*)(rsrc + (size_t)n*256 + (w << 1));
        int ws = (((w >> 2) ^ ((n >> 1) & 3)) << 2) | (w & 3);
        ((uint_t*)Kh)[n*16 + ws] = (uint_t)f2h(v.x) | ((uint_t)f2h(v.y) << 16);
      }
      const float* asrc = (pass ? ATK : AT) + (size_t)b*49*256 + h*32;
      for (int t = tid; t < 784; t += 256){
        int a = t >> 4, w = t & 15;
        const float2 v = *(const float2*)(asrc + (size_t)a*256 + (w << 1));
        int ws = (((w >> 2) ^ ((a >> 1) & 3)) << 2) | (w & 3);
        ((uint_t*)Ah)[a*16 + ws] = (uint_t)f2h(v.x) | ((uint_t)f2h(v.y) << 16);
      }
    }
    __syncthreads();
    {
      float lscl = pass ? SCL : 0.03125f;
      int ag = wv*16 + mrow;
      half8 bfr = *(const half8*)&Ah[ag*32 + sw8];
      #pragma unroll 1
      for (int mt = 0; mt < 13; ++mt){
        half8 afr = *(const half8*)&Kh[(mt*16 + mrow)*32 + sw8];
        f32x4 c = (f32x4){0.f,0.f,0.f,0.f};
        c = __builtin_amdgcn_mfma_f32_16x16x32_f16(afr, bfr, c, 0, 0, 0);
        #pragma unroll
        for (int r = 0; r < 4; ++r){
          int n = mt*16 + quad*4 + r;
          if (n < 196 && ag < 49){
            float e = __expf(fmaf(c[r], lscl, AB[((size_t)h*196 + n)*49 + ag]));
            ST[n*72 + ag] = f2h(e);
          }
        }
      }
    }
    __syncthreads();
    if (tid < 196){
      float s = 0.f;
      #pragma unroll
      for (int u = 0; u < 7; ++u){
        short8 v8 = *(const short8*)&ST[tid*72 + u*8];
        #pragma unroll
        for (int e = 0; e < 8; ++e) s += h2f((ushort_t)v8[e]);
      }
      invs[tid] = 1.f / s;
    }
    __syncthreads();
    {
      int i = 0;
      #pragma unroll 1
      for (int mt = wv; mt < 13; mt += 4, ++i){
        #pragma unroll
        for (int nt = 0; nt < 2; ++nt){
          f32x4 c = (f32x4){0.f,0.f,0.f,0.f};
          #pragma unroll
          for (int ks = 0; ks < 2; ++ks){
            half8 afr = *(const half8*)&ST[(mt*16 + mrow)*72 + ks*32 + quad*8];
            half8 bfr = *(const half8*)&AGVt[(nt*16 + mrow)*64 + ((((ks*4 + quad) ^ (mrow & 7)) & 7) << 3)];
            c = __builtin_amdgcn_mfma_f32_16x16x32_f16(afr, bfr, c, 0, 0, 0);
          }
          #pragma unroll
          for (int r = 0; r < 4; ++r){
            int n = mt*16 + quad*4 + r;
            if (n < 196) acc[i][nt][r] = fmaf(c[r], invs[n], acc[i][nt][r]);
          }
        }
      }
    }
    __syncthreads();   // ST free after this (last pass ends here)
  }
  // ---- store via LDS out-tile (overlay ST): TO[196][33] floats = 25.9KB <= 30KB ----
  {
    float* TO = (float*)ST;
    int i = 0;
    #pragma unroll 1
    for (int mt = wv; mt < 13; mt += 4, ++i){
      #pragma unroll
      for (int nt = 0; nt < 2; ++nt){
        #pragma unroll
        for (int r = 0; r < 4; ++r){
          int n = mt*16 + quad*4 + r;
          if (n < 196) TO[n*33 + nt*16 + mrow] = acc[i][nt][r];
        }
      }
    }
    __syncthreads();
    float* xb = XO + (size_t)b*196*256 + h*32;
    for (int t = tid; t < 1568; t += 256){
      int n = t >> 3, q = (t & 7)*4;
      f32x4 v = { TO[n*33 + q], TO[n*33 + q + 1], TO[n*33 + q + 2], TO[n*33 + q + 3] };
      *(f32x4*)(xb + (size_t)n*256 + q) = v;
    }
  }
}

// ---------- fused depthwise conv: dwc(conv_x2 + qc), bias 2*dwc_b, accumulated into XO ----------
// Accumulate now routed through an LDS out-tile (overlaying pl after compute):
// the old dst[j*256] += acc[j] was a fully-scattered 4B RMW (64 lines/instr);
// now 196 rows x 8 float4 coalesced RMW (8x128B segments per wave). Same values
// added in the same order -> bit-identical.
__global__ __launch_bounds__(256) void k_dwc(const float* __restrict__ Y, const float* __restrict__ CMAP,
    const float* __restrict__ dw, const float* __restrict__ db, float* __restrict__ XO){
  int b = blockIdx.x >> 3, cg = blockIdx.x & 7;
  int c0 = cg*32;
  __shared__ __align__(16) float pl[32*360];   // planes; reused as TO[196][33] after compute
  int tid = threadIdx.x;
  for (int t = tid; t < 32*360; t += 256) pl[t] = 0.f;
  __syncthreads();
  const float* yq = Y + (size_t)b*YSTR + QOFF;
  for (int t = tid; t < 32*196; t += 256){
    int cl = t & 31, s = t >> 5;
    int c = c0 + cl;
    int G = s*256 + c;                 // head-major flat index for conv_x2's scramble
    int hh = G / 6272;
    int rem = G - hh*6272;
    int n = rem >> 5, d = rem & 31;
    float cx2 = CMAP[b*256 + c] * yq[n*256 + hh*32 + d];   // sigmoid(cmap)*qs
    float qc  = yq[G];                                     // qc collapses to identity gather
    float v = SCL*(cx2 + qc);
    int i = s/14, j = s - i*14;
    pl[cl*360 + (i+2)*20 + j + 2] = v;
  }
  __syncthreads();
  // compute both work items into registers (448 items over 256 threads)
  float acc0[14], acc1[14];
  int cl0 = tid/14, r0 = tid - cl0*14;
  {
    float w25[25];
    #pragma unroll
    for (int u = 0; u < 25; ++u) w25[u] = dw[(c0 + cl0)*25 + u];
    float b2 = 2.f*db[c0 + cl0];
    #pragma unroll
    for (int j = 0; j < 14; ++j) acc0[j] = b2;
    conv5x5_row(&pl[cl0*360], r0, w25, acc0);
  }
  int t1 = tid + 256;
  int cl1 = t1/14, r1 = t1 - cl1*14;
  if (t1 < 448){
    float w25[25];
    #pragma unroll
    for (int u = 0; u < 25; ++u) w25[u] = dw[(c0 + cl1)*25 + u];
    float b2 = 2.f*db[c0 + cl1];
    #pragma unroll
    for (int j = 0; j < 14; ++j) acc1[j] = b2;
    conv5x5_row(&pl[cl1*360], r1, w25, acc1);
  }
  __syncthreads();            // all pl reads done -> safe to overlay
  float* TO = pl;             // [196][33]
  #pragma unroll
  for (int j = 0; j < 14; ++j) TO[(r0*14 + j)*33 + cl0] = acc0[j];
  if (t1 < 448){
    #pragma unroll
    for (int j = 0; j < 14; ++j) TO[(r1*14 + j)*33 + cl1] = acc1[j];
  }
  __syncthreads();
  float* xb = XO + (size_t)b*196*256 + c0;
  for (int t = tid; t < 1568; t += 256){
    int n = t >> 3, q = (t & 7)*4;
    f32x4 v = *(f32x4*)(xb + (size_t)n*256 + q);
    v[0] += TO[n*33 + q];
    v[1] += TO[n*33 + q + 1];
    v[2] += TO[n*33 + q + 2];
    v[3] += TO[n*33 + q + 3];
    *(f32x4*)(xb + (size_t)n*256 + q) = v;
  }
}

// ---------- final projection: out = XO @ proj_w^T + proj_b ----------
__global__ __launch_bounds__(256) void k_proj(const float* __restrict__ XO, const float* __restrict__ WT,
    const float* __restrict__ pbias, float* __restrict__ OUT){
  int bb = blockIdx.x / 7, nt = blockIdx.x % 7;
  int n0 = nt*28;
  int c = threadIdx.x;
  const float* xb = XO + ((size_t)bb*196 + n0)*256;
  float acc[28];
  #pragma unroll
  for (int r = 0; r < 28; ++r) acc[r] = 0.f;
  for (int k = 0; k < 256; k += 4){
    float w0 = WT[(k+0)*256 + c];
    float w1 = WT[(k+1)*256 + c];
    float w2 = WT[(k+2)*256 + c];
    float w3 = WT[(k+3)*256 + c];
    #pragma unroll
    for (int r = 0; r < 28; ++r){
      float4 xv = *(const float4*)(xb + r*256 + k);   // uniform address -> scalar/L1 path
      acc[r] = fmaf(xv.x, w0, fmaf(xv.y, w1, fmaf(xv.z, w2, fmaf(xv.w, w3, acc[r]))));
    }
  }
  float bv = pbias[c];
  float* dst = OUT + ((size_t)bb*196 + n0)*256 + c;
  #pragma unroll
  for (int r = 0; r < 28; ++r) dst[r*256] = acc[r] + bv;
}

extern "C" void kernel_launch(void* const* d_in, const int* in_sizes, int n_in,
                              void* d_out, int out_size, void* d_ws, size_t ws_size,
                              hipStream_t stream){
  (void)in_sizes; (void)n_in; (void)out_size; (void)ws_size;
  const float* x       = (const float*)d_in[0];
  const float* lka_w   = (const float*)d_in[3];
  const float* lka_b   = (const float*)d_in[4];
  const float* conv5_w = (const float*)d_in[5];
  const float* conv5_b = (const float*)d_in[6];
  const float* caa1_w  = (const float*)d_in[7];
  const float* caa1_b  = (const float*)d_in[8];
  const float* caa2_w  = (const float*)d_in[9];
  const float* caa2_b  = (const float*)d_in[10];
  const float* cam1_w  = (const float*)d_in[11];
  const float* cam1_b  = (const float*)d_in[12];
  const float* cam2_w  = (const float*)d_in[13];
  const float* cam2_b  = (const float*)d_in[14];
  const float* sa_w    = (const float*)d_in[15];
  const float* sa_b    = (const float*)d_in[16];
  const float* ci1_w   = (const float*)d_in[17];
  const float* ci1_b   = (const float*)d_in[18];
  const float* bn_g    = (const float*)d_in[19];
  const float* bn_b    = (const float*)d_in[20];
  const float* ci2_w   = (const float*)d_in[21];
  const float* ci2_b   = (const float*)d_in[22];
  const float* rpbt    = (const float*)d_in[23];
  const float* an_bias = (const float*)d_in[24];
  const float* na_bias = (const float*)d_in[25];
  const float* ah_bias = (const float*)d_in[26];
  const float* aw_bias = (const float*)d_in[27];
  const float* ha_bias = (const float*)d_in[28];
  const float* wa_bias = (const float*)d_in[29];
  const float* dwc_w   = (const float*)d_in[30];
  const float* dwc_b   = (const float*)d_in[31];
  const float* proj_w  = (const float*)d_in[32];
  const float* proj_b  = (const float*)d_in[33];
  float* out = (float*)d_out;
  float* ws = (float*)d_ws;

  float* Y    = ws + WS_Y;
  float* V5   = ws + WS_V5;
  float* AT   = ws + WS_AT;
  float* ATK  = ws + WS_ATK;
  float* CHG  = ws + WS_CHG;   // avg, then chg in-place
  float* CMAP = ws + WS_CMAP;
  float* PBT  = ws + WS_PBT;
  float* AB   = ws + WS_AB;
  float* X1S  = ws + WS_X1S;
  float* AGV  = ws + WS_AGV;
  float* XO   = ws + WS_XO;
  float* WT   = ws + WS_WT;
  ushort_t* Wh = (ushort_t*)(ws + WS_CWT);
  float* MXp  = ws + WS_MX;
  float* MKp  = ws + WS_MK;

  k_pbab <<<602, 256, 0, stream>>>(an_bias, ah_bias, aw_bias, na_bias, ha_bias, wa_bias, PBT, AB);
  k_wprep<<<1056, 256, 0, stream>>>(conv5_w, Wh, proj_w, WT);
  k_lka  <<<1024, 256, 0, stream>>>(x, lka_w, lka_b, Y);
  k_conv5<<<512, 256, 0, stream>>>(Y, Wh, conv5_b, V5);
  k_pool <<<256, 256, 0, stream>>>(Y, AT, ATK);
  k_cbam_a2<<<1024, 256, 0, stream>>>(V5, CHG, MXp);
  k_cbam_b2<<<128, 512, 0, stream>>>(V5, CHG, MXp, caa1_w, caa1_b, caa2_w, caa2_b,
                                     cam1_w, cam1_b, cam2_w, cam2_b, sa_w, sa_b, MKp);
  k_attn3<<<1024, 512, 0, stream>>>(Y, rpbt, X1S);
  k_cinter<<<128, 256, 0, stream>>>(X1S, ci1_w, ci1_b, bn_g, bn_b, ci2_w, ci2_b, CMAP);
  k_agentv<<<1024, 256, 0, stream>>>(Y, V5, CHG, MKp, AT, ATK, PBT, AGV);
  k_xo1  <<<1024, 256, 0, stream>>>(Y, AT, ATK, AB, AGV, XO);
  k_dwc  <<<1024, 256, 0, stream>>>(Y, CMAP, dwc_w, dwc_b, XO);
  k_proj <<<896, 256, 0, stream>>>(XO, WT, proj_b, out);
}

// Round 11
// 730.250 us; speedup vs baseline: 1.0165x; 1.0165x over previous
//
#include <hip/hip_runtime.h>

// Problem constants
#define NB    128
#define NC    256
#define NPOS  196
#define NHEAD 8
#define NAG   49
#define YSTR  150528      // 768*196 per-batch y floats
#define VOFF  50176       // v_raw offset inside y (256*196)
#define QOFF  100352      // q_raw offset inside y (512*196)
#define SCL   0.17677669529663687f   // 32^-0.5

// Workspace layout (floats). Total = 38,885,440 floats = 155.5 MB.
#define WS_Y    0u
#define WS_V5   19267584u
#define WS_AT   25690112u
#define WS_ATK  27295744u
#define WS_CHG  28901376u   // avg -> overwritten in-place by chg (per-b partition)
#define WS_CMAP 28934144u
#define WS_PBT  28966912u
#define WS_AB   29043744u
#define WS_X1S  29120576u
#define WS_AGV  29153344u
#define WS_XO   30758976u
#define WS_WT   37181504u
#define WS_CWT  37247040u   // Wh: 1.6M ushort (fp16 conv5 weights, [tap][co][ci]) -> ends 38066240
#define WS_MX   38066240u   // [128][256] channel max (spare tail)
#define WS_MK   38099008u   // [128][196] spatial mask (spare tail; ends 38124096 < total)

typedef __attribute__((ext_vector_type(8))) _Float16 half8;
typedef __attribute__((ext_vector_type(8))) short short8;
typedef __attribute__((ext_vector_type(4))) short short4v;
typedef __attribute__((ext_vector_type(4))) float f32x4;
typedef unsigned short ushort_t;
typedef unsigned int uint_t;

__device__ __forceinline__ float sigmoidf_(float x){ return 1.0f/(1.0f+__expf(-x)); }

__device__ __forceinline__ ushort_t f2h(float x){
  _Float16 h = (_Float16)x; return __builtin_bit_cast(ushort_t, h);
}
__device__ __forceinline__ float h2f(ushort_t u){
  return (float)__builtin_bit_cast(_Float16, u);
}

// bilinear upsample 7x7 -> 14x14 sample at (i,j), matching reference grid()
__device__ __forceinline__ float bilin7(const float* __restrict__ src, int i, int j){
  float pi = fmaxf(0.5f*(float)i - 0.25f, 0.f);
  int i0 = (int)pi; if (i0 > 6) i0 = 6;
  int i1 = i0 + 1;  if (i1 > 6) i1 = 6;
  float li = pi - (float)i0;
  float pj = fmaxf(0.5f*(float)j - 0.25f, 0.f);
  int j0 = (int)pj; if (j0 > 6) j0 = 6;
  int j1 = j0 + 1;  if (j1 > 6) j1 = 6;
  float lj = pj - (float)j0;
  float v00 = src[i0*7+j0], v01 = src[i0*7+j1];
  float v10 = src[i1*7+j0], v11 = src[i1*7+j1];
  float t0 = v00*(1.f-lj) + v01*lj;
  float t1 = v10*(1.f-lj) + v11*lj;
  return t0*(1.f-li) + t1*li;
}

// 5x5 conv over a zero-padded [18][20] plane, producing one 14-wide output row r.
__device__ __forceinline__ void conv5x5_row(const float* __restrict__ plane, int r,
                                            const float* __restrict__ w25, float* acc14){
  #pragma unroll
  for (int di = 0; di < 5; ++di){
    const float4* pr = (const float4*)(plane + (r+di)*20);
    float4 p0 = pr[0], p1 = pr[1], p2 = pr[2], p3 = pr[3], p4 = pr[4];
    float row[20] = {p0.x,p0.y,p0.z,p0.w, p1.x,p1.y,p1.z,p1.w, p2.x,p2.y,p2.z,p2.w,
                     p3.x,p3.y,p3.z,p3.w, p4.x,p4.y,p4.z,p4.w};
    #pragma unroll
    for (int dj = 0; dj < 5; ++dj){
      float w = w25[di*5+dj];
      #pragma unroll
      for (int j = 0; j < 14; ++j) acc14[j] = fmaf(row[j+dj], w, acc14[j]);
    }
  }
}

// ---------- prep kernels ----------
// merged pb+ab: blocks [0,301) -> PBT, [301,602) -> AB
__global__ void k_pbab(const float* __restrict__ an, const float* __restrict__ ah,
                       const float* __restrict__ aw, const float* __restrict__ na,
                       const float* __restrict__ ha, const float* __restrict__ wa,
                       float* __restrict__ PBT, float* __restrict__ AB){
  int bid = blockIdx.x;
  int which = (bid >= 301);
  int t = (which ? bid - 301 : bid)*256 + threadIdx.x;
  if (t >= NHEAD*NPOS*NAG) return;
  int a = t % NAG;
  int r = t / NAG;
  int n = r % NPOS;
  int h = r / NPOS;
  int i = n/14, j = n - (n/14)*14;
  if (!which){
    float v = bilin7(an + ((size_t)h*NAG + a)*49, i, j);
    v += ah[((size_t)h*NAG + a)*14 + i] + aw[((size_t)h*NAG + a)*14 + j];
    PBT[t] = v;   // [h][n][a]
  } else {
    float v = bilin7(na + ((size_t)h*NAG + a)*49, i, j);
    v += ha[((size_t)h*14 + i)*NAG + a] + wa[((size_t)h*14 + j)*NAG + a];
    AB[t] = v;    // [h][n][a]
  }
}

// merged weight prep: blocks [0,800) -> conv5 fp16 weights (8 elems/thread),
// blocks [800,1056) -> proj_w transpose.
__global__ void k_wprep(const float* __restrict__ cw, ushort_t* __restrict__ Wh,
                        const float* __restrict__ pw, float* __restrict__ WT){
  int bid = blockIdx.x;
  if (bid < 800){
    int base = (bid*256 + threadIdx.x)*8;       // < 1638400; 8 | 256 so r uniform
    int r   = base >> 8;
    int co  = r & 255;
    int tap = r >> 8;
    int ci0 = base & 255;
    const float* srcb = cw + (size_t)co*6400 + (size_t)ci0*25 + tap;
    short8 o;
    #pragma unroll
    for (int e = 0; e < 8; ++e) o[e] = (short)f2h(srcb[e*25]);
    *(short8*)(Wh + base) = o;                  // Wh[tap][co][ci]
  } else {
    int t = (bid - 800)*256 + threadIdx.x;      // < 65536
    int k = t >> 8, c = t & 255;
    WT[t] = pw[c*256 + k];                      // WT[k][c] = proj_w[c][k]
  }
}

// ---------- lka depthwise-ish conv (groups=256, 3 outputs per input channel) ----------
__global__ __launch_bounds__(256) void k_lka(const float* __restrict__ x, const float* __restrict__ lw,
                                             const float* __restrict__ lb, float* __restrict__ Y){
  int b = blockIdx.x >> 3, gb = blockIdx.x & 7;
  int g0 = gb*32;                               // input channels [g0,g0+32)
  __shared__ __align__(16) float pl[32*360];    // [ch][18*20] padded planes
  int tid = threadIdx.x;
  for (int t = tid; t < 32*360; t += 256) pl[t] = 0.f;
  __syncthreads();
  for (int t = tid; t < 32*196; t += 256){
    int gl = t & 31, s = t >> 5;
    int i = s/14, j = s - i*14;
    pl[gl*360 + (i+2)*20 + j + 2] = x[((size_t)b*196 + s)*256 + g0 + gl];
  }
  __syncthreads();
  for (int t = tid; t < 96*14; t += 256){
    int ocl = t/14, r = t - ocl*14;
    int o  = g0*3 + ocl;          // output channel; uses input channel o/3
    int gl = ocl/3;
    float w25[25];
    #pragma unroll
    for (int u = 0; u < 25; ++u) w25[u] = lw[o*25 + u];
    float acc[14];
    float bv = lb[o];
    #pragma unroll
    for (int j = 0; j < 14; ++j) acc[j] = bv;
    conv5x5_row(&pl[gl*360], r, w25, acc);
    float* dst = Y + ((size_t)b*768 + o)*196 + r*14;
    #pragma unroll
    for (int j = 0; j < 14; ++j) dst[j] = acc[j];
  }
}

// ---------- conv5 via fp16 MFMA implicit GEMM, W double-buffered (round-7 winner) ----------
__global__ __launch_bounds__(256, 2) void k_conv5(const float* __restrict__ Y,
    const ushort_t* __restrict__ Wh, const float* __restrict__ cb, float* __restrict__ V5){
  int b = blockIdx.x >> 2, cog = blockIdx.x & 3;
  int co0 = cog*64;
  __shared__ __align__(16) ushort_t Pt[360*40];       // fp16 A: [pos][4 chunks of 8ci + pad]
  __shared__ __align__(16) ushort_t Wsm[2*5*64*40];   // fp16 B, double-buffered
  float* T = (float*)Wsm;                             // epilogue transpose (buffer 0)
  int tid  = threadIdx.x;
  int lane = tid & 63, wv = tid >> 6;
  int mrow = lane & 15, quad = lane >> 4;

  for (int t = tid; t < 7200; t += 256) ((uint_t*)Pt)[t] = 0;

  int prow[4];
  #pragma unroll
  for (int mt = 0; mt < 4; ++mt){
    int s = wv*64 + mt*16 + mrow;
    int p0 = 0;
    if (s < 196){ int i = s/14, j = s - i*14; p0 = i*20 + j; }
    prow[mt] = p0;
  }

  f32x4 acc[4][4];
  #pragma unroll
  for (int mt = 0; mt < 4; ++mt)
    #pragma unroll
    for (int nt = 0; nt < 4; ++nt) acc[mt][nt] = (f32x4){0.f,0.f,0.f,0.f};

  const float* src = Y + (size_t)b*YSTR + VOFF;   // v_raw [ci][s]
  int wco = tid >> 2, wpart = tid & 3;            // W-staging roles
  const ushort_t* wbase = Wh + ((size_t)(co0 + wco))*256 + wpart*8;  // + tap*65536 + cc*32

  short8 wreg[5];
  #pragma unroll
  for (int tp = 0; tp < 5; ++tp)
    wreg[tp] = *(const short8*)(wbase + (size_t)tp*65536);

  #pragma unroll 1
  for (int cc = 0; cc < 8; ++cc){
    __syncthreads();              // Pt free to overwrite (prev cc compute done)
    for (int t = tid; t < 784; t += 256){
      int pos = t >> 2, ch = t & 3;
      int i = pos/14, j = pos - i*14;
      int p = (i+2)*20 + j + 2;
      const float* s0 = src + (size_t)(cc*32 + ch*8)*196 + pos;
      short8 pk;
      #pragma unroll
      for (int e = 0; e < 4; ++e){
        float v0 = s0[(2*e)*196];
        float v1 = s0[(2*e+1)*196];
        pk[2*e]   = (short)f2h(v0);
        pk[2*e+1] = (short)f2h(v1);
      }
      *(short8*)&Pt[p*40 + ch*8] = pk;
    }
    #pragma unroll 1
    for (int di = 0; di < 5; ++di){
      int u = cc*5 + di;
      ushort_t* wbuf = Wsm + (u & 1)*12800;
      #pragma unroll
      for (int tp = 0; tp < 5; ++tp)
        *(short8*)&wbuf[(tp*64 + wco)*40 + wpart*8] = wreg[tp];
      if (u < 39){
        int di1 = di + 1, cc1 = cc;
        if (di1 == 5){ di1 = 0; ++cc1; }
        #pragma unroll
        for (int tp = 0; tp < 5; ++tp)
          wreg[tp] = *(const short8*)(wbase + (size_t)(di1*5 + tp)*65536 + cc1*32);
      }
      __syncthreads();      // fences A writes (di=0) and this step's W writes
      #pragma unroll
      for (int dj = 0; dj < 5; ++dj){
        half8 a[4], bb[4];
        #pragma unroll
        for (int nt = 0; nt < 4; ++nt){
          int co = nt*16 + mrow;
          bb[nt] = *(const half8*)&wbuf[(dj*64 + co)*40 + quad*8];
        }
        #pragma unroll
        for (int mt = 0; mt < 4; ++mt){
          int p = prow[mt] + di*20 + dj;
          a[mt] = *(const half8*)&Pt[p*40 + quad*8];
        }
        #pragma unroll
        for (int mt = 0; mt < 4; ++mt)
          #pragma unroll
          for (int nt = 0; nt < 4; ++nt)
            acc[mt][nt] = __builtin_amdgcn_mfma_f32_16x16x32_f16(a[mt], bb[nt], acc[mt][nt], 0, 0, 0);
      }
    }
  }

  // epilogue: transpose through LDS (T = Wsm buffer 0), stores into scrambled v5
  #pragma unroll
  for (int hf = 0; hf < 2; ++hf){
    __syncthreads();
    #pragma unroll
    for (int ntl = 0; ntl < 2; ++ntl){
      int nt = hf*2 + ntl;
      int col = ntl*16 + mrow;            // co local within half (0..31)
      #pragma unroll
      for (int mt = 0; mt < 4; ++mt){
        int sbase = wv*64 + mt*16 + quad*4;
        #pragma unroll
        for (int r = 0; r < 4; ++r){
          int s = sbase + r;
          if (s < 196) T[col*200 + s] = acc[mt][nt][r];
        }
      }
    }
    __syncthreads();
    for (int t = tid; t < 6272; t += 256){
      int cl = t / 196;                   // co local 0..31
      int f = (co0 + hf*32)*196 + t;
      float val = T[t + cl*4] + cb[co0 + hf*32 + cl];
      V5[(size_t)b*50176 + (size_t)(f & 255)*196 + (f >> 8)] = val;
    }
  }
}

// ---------- agent token pooling (256 blocks: channel-half x agent-half split) ----------
__global__ __launch_bounds__(256) void k_pool(const float* __restrict__ Y, float* __restrict__ AT, float* __restrict__ ATK){
  int b = blockIdx.x >> 1, half = blockIdx.x & 1;
  int c = (threadIdx.x & 127) + half*128;
  int a0 = (threadIdx.x >> 7) ? 25 : 0;
  int a1 = (threadIdx.x >> 7) ? 49 : 25;
  const float* qp = Y + ((size_t)b*768 + 512 + c)*196;
  const float* kp = Y + ((size_t)b*768 + c)*196;
  for (int a = a0; a < a1; ++a){
    int p1 = a/7, p2 = a - p1*7;
    int s = p1*28 + p2*2;
    float q0 = qp[s], q1 = qp[s+1], q2 = qp[s+14], q3 = qp[s+15];
    AT[((size_t)b*49 + a)*256 + c] = 0.25f*(q0+q1+q2+q3);
    float k0 = kp[s], k1 = kp[s+1], k2 = kp[s+14], k3 = kp[s+15];
    ATK[((size_t)b*49 + a)*256 + c] = fmaxf(fmaxf(k0,k1), fmaxf(k2,k3));
  }
}

// ---------- cbam stage A: per-channel stats, high parallelism (1024 blocks) ----------
// 32 channels per block (8 iters/wave), coalesced float4 + 64-lane shuffle reduce.
__global__ __launch_bounds__(256) void k_cbam_a2(const float* __restrict__ V5,
    float* __restrict__ AVG, float* __restrict__ MX){
  int b = blockIdx.x >> 3, oct = blockIdx.x & 7;
  int tid = threadIdx.x, wv = tid >> 6, lane = tid & 63;
  const float* v5b = V5 + (size_t)b*50176;
  #pragma unroll
  for (int i = 0; i < 8; ++i){
    int c = oct*32 + i*4 + wv;
    float s, m;
    if (lane < 49){
      float4 v = *(const float4*)(v5b + c*196 + lane*4);
      s = v.x + v.y + v.z + v.w;
      m = fmaxf(fmaxf(v.x, v.y), fmaxf(v.z, v.w));
    } else { s = 0.f; m = -1e30f; }
    #pragma unroll
    for (int off = 1; off < 64; off <<= 1){
      s += __shfl_xor(s, off);
      m = fmaxf(m, __shfl_xor(m, off));
    }
    if (lane == 0){
      AVG[b*256 + c] = s*(1.0f/196.0f);
      MX[b*256 + c]  = m;
    }
  }
}

// ---------- cbam stage B: MLP -> chg, spatial mask -> MK. V5 NOT modified ----------
__global__ __launch_bounds__(512) void k_cbam_b2(const float* __restrict__ V5,
    float* __restrict__ AVGCHG, const float* __restrict__ MX,
    const float* __restrict__ caa1w, const float* __restrict__ caa1b,
    const float* __restrict__ caa2w, const float* __restrict__ caa2b,
    const float* __restrict__ cam1w, const float* __restrict__ cam1b,
    const float* __restrict__ cam2w, const float* __restrict__ cam2b,
    const float* __restrict__ saw, const float* __restrict__ sab,
    float* __restrict__ MK){
  int b = blockIdx.x;
  __shared__ float avg[256], mx[256], t1[16], t2[16], chg[256];
  __shared__ float sp[2][196], sx[2][196];
  __shared__ float mp[22*22], xp[22*22];
  int tid = threadIdx.x;
  if (tid < 256) avg[tid] = AVGCHG[b*256 + tid];
  else           mx[tid - 256] = MX[b*256 + tid - 256];
  for (int t = tid; t < 484; t += 512){ mp[t] = 0.f; xp[t] = 0.f; }
  __syncthreads();

  if (tid < 16){
    float a1 = caa1b[tid], a2 = cam1b[tid];
    #pragma unroll 4
    for (int k = 0; k < 256; ++k){
      a1 = fmaf(caa1w[(tid*256 + k)*9 + 4], avg[k], a1);   // 3x3 center tap
      a2 = fmaf(cam1w[tid*256 + k], mx[k], a2);            // 1x1
    }
    t1[tid] = fmaxf(a1, 0.f);
    t2[tid] = fmaxf(a2, 0.f);
  }
  __syncthreads();
  if (tid < 256){
    float y1 = caa2b[tid], y2 = cam2b[tid];
    #pragma unroll
    for (int k = 0; k < 16; ++k){
      y1 = fmaf(caa2w[(tid*16 + k)*9 + 4], t1[k], y1);
      y2 = fmaf(cam2w[tid*16 + k], t2[k], y2);
    }
    float g = sigmoidf_(sigmoidf_(y1) + sigmoidf_(y2));
    chg[tid] = g;
    AVGCHG[b*256 + tid] = g;            // chg overwrites avg (avg already in LDS)
  }
  __syncthreads();

  // spatial mean/max over channels, split across 2 half-channel groups
  {
    int g = tid >> 8, pos = tid & 255;
    if (pos < 196){
      const float* vb = V5 + (size_t)b*50176 + pos;
      float s = 0.f, m = -1e30f;
      for (int c = g*128; c < g*128 + 128; ++c){
        float v = chg[c] * vb[c*196];
        s += v; m = fmaxf(m, v);
      }
      sp[g][pos] = s; sx[g][pos] = m;
    }
  }
  __syncthreads();
  if (tid < 196){
    int i = tid/14, j = tid - i*14;
    mp[(i+4)*22 + j+4] = (sp[0][tid] + sp[1][tid])*(1.f/256.f);
    xp[(i+4)*22 + j+4] = fmaxf(sx[0][tid], sx[1][tid]);
  }
  __syncthreads();
  if (tid < 196){
    int i = tid/14, j = tid - i*14;
    float acc = sab[0];
    for (int di = 0; di < 9; ++di){
      #pragma unroll
      for (int dj = 0; dj < 9; ++dj){
        acc = fmaf(mp[(i+di)*22 + j+dj], saw[di*9+dj], acc);
        acc = fmaf(xp[(i+di)*22 + j+dj], saw[81 + di*9+dj], acc);
      }
    }
    MK[(size_t)b*196 + tid] = sigmoidf_(acc);
  }
}

// ---------- big NxN attention via MFMA, 3-segment version (round-6) ----------
__global__ __launch_bounds__(512, 4) void k_attn3(const float* __restrict__ Y,
    const float* __restrict__ rpbt, float* __restrict__ X1S){
  int b = blockIdx.x >> 3, h = blockIdx.x & 7;
  __shared__ __align__(16) ushort_t Qh[208*32];    // fp16 q*SCL rows, chunk-swizzled
  __shared__ __align__(16) ushort_t Kh[208*32];    // fp16 k rows, chunk-swizzled
  __shared__ __align__(16) ushort_t E[80*208];     // fp16 exp-scores [n-local][j]
  __shared__ float rp[736];
  __shared__ int   rpo[208];
  __shared__ float pl2[80][2];                     // lsum halves per row
  __shared__ float invl[80];
  __shared__ float wj[208];
  __shared__ float wpart[8][208];
  __shared__ float xpart[16][32];
  int tid = threadIdx.x, wv = tid >> 6, lane = tid & 63;
  int mrow = lane & 15, quad = lane >> 4;
  int sw8 = ((quad ^ ((mrow >> 1) & 3)) << 3);     // 64B-row read swizzle
  const float* yb = Y + (size_t)b*YSTR;

  for (int t = tid; t < 736; t += 512) rp[t] = (t < 729) ? rpbt[t*8 + h] : 0.f;
  for (int j = tid; j < 208; j += 512){
    int jc = (j < 196) ? j : 195;
    int rj = jc/14;
    rpo[j] = rj*27 + (jc - rj*14);
    wj[j] = 0.f;
  }
  for (int t = tid; t < 384; t += 512){            // zero rows 196..207 of Qh/Kh
    int arr = t >= 192; int u = t - arr*192;
    ((uint_t*)(arr ? Kh : Qh))[3136 + u] = 0;
  }
  for (int t = tid; t < 3136; t += 512){
    int n = t >> 4, w = t & 15;
    int ws = (((w >> 2) ^ ((n >> 1) & 3)) << 2) | (w & 3);
    const float2 qv = *(const float2*)(yb + QOFF + (size_t)n*256 + h*32 + (w << 1));
    ((uint_t*)Qh)[n*16 + ws] = (uint_t)f2h(qv.x*SCL) | ((uint_t)f2h(qv.y*SCL) << 16);
    const float2 kv = *(const float2*)(yb + (size_t)n*256 + h*32 + (w << 1));
    ((uint_t*)Kh)[n*16 + ws] = (uint_t)f2h(kv.x) | ((uint_t)f2h(kv.y) << 16);
  }
  __syncthreads();

  int mt0 = (wv & 1) ? 7 : 0;
  int mt1 = (wv & 1) ? 13 : 7;

  #pragma unroll 1
  for (int seg = 0; seg < 3; ++seg){
    int base = (seg == 0) ? 0 : (seg == 1) ? 80 : 144;
    int ntl  = (seg == 0) ? 5 : 4;
    int segrows = ntl*16;
    int vrows = 196 - base; if (vrows > segrows) vrows = segrows;

    #pragma unroll 1
    for (int ncl = (wv >> 1); ncl < ntl; ncl += 4){
      int n = base + ncl*16 + mrow;
      half8 bfr = *(const half8*)&Qh[n*32 + sw8];
      int nclamp = (n < 196) ? n : 195;
      int rin = nclamp/14, cin = nclamp - rin*14;
      int bidxn = (rin + 13)*27 + (cin + 13);
      float lsum = 0.f;
      #pragma unroll 1
      for (int mt = mt0; mt < mt1; ++mt){
        half8 afr = *(const half8*)&Kh[(mt*16 + mrow)*32 + sw8];
        f32x4 c = (f32x4){0.f,0.f,0.f,0.f};
        c = __builtin_amdgcn_mfma_f32_16x16x32_f16(afr, bfr, c, 0, 0, 0);
        int j0 = mt*16 + quad*4;
        int4 ro = *(const int4*)&rpo[j0];
        short4v pk;
        #pragma unroll
        for (int r = 0; r < 4; ++r){
          int j = j0 + r;
          int roff = (r == 0) ? ro.x : (r == 1) ? ro.y : (r == 2) ? ro.z : ro.w;
          float e = (j < 196) ? __expf(c[r] + rp[bidxn - roff]) : 0.f;
          lsum += e;
          pk[r] = (short)f2h(e);
        }
        if (n < 196) *(short4v*)&E[(n - base)*208 + j0] = pk;
      }
      lsum += __shfl_xor(lsum, 16);
      lsum += __shfl_xor(lsum, 32);
      if (quad == 0) pl2[n - base][wv & 1] = lsum;
    }
    __syncthreads();
    for (int t = tid; t < vrows; t += 512) invl[t] = 1.f/(pl2[t][0] + pl2[t][1]);
    __syncthreads();

    {
      int j0 = lane*4;
      if (j0 < 208){
        float a0=0.f,a1=0.f,a2=0.f,a3=0.f;
        #pragma unroll 1
        for (int nl = wv; nl < vrows; nl += 8){
          float iv = invl[nl];
          short4v ev = *(const short4v*)&E[nl*208 + j0];
          a0 = fmaf(h2f((ushort_t)ev[0]), iv, a0);
          a1 = fmaf(h2f((ushort_t)ev[1]), iv, a1);
          a2 = fmaf(h2f((ushort_t)ev[2]), iv, a2);
          a3 = fmaf(h2f((ushort_t)ev[3]), iv, a3);
        }
        *(f32x4*)&wpart[wv][j0] = (f32x4){a0,a1,a2,a3};
      }
    }
    __syncthreads();
    for (int j = tid; j < 208; j += 512){
      float s = wj[j];
      #pragma unroll
      for (int g = 0; g < 8; ++g) s += wpart[g][j];
      wj[j] = s;
    }
    __syncthreads();   // wpart/E/pl2/invl free for next segment
  }

  {
    int d = tid & 31, g = tid >> 5;                // 16 groups x 13 j's
    float s = 0.f;
    #pragma unroll 1
    for (int u = 0; u < 13; ++u){
      int j = g*13 + u;
      s = fmaf(wj[j], yb[VOFF + (size_t)j*256 + h*32 + d], s);
    }
    xpart[g][d] = s;
  }
  __syncthreads();
  if (tid < 32){
    float s = 0.f;
    #pragma unroll
    for (int g2 = 0; g2 < 16; ++g2) s += xpart[g2][tid];
    X1S[(size_t)b*256 + h*32 + tid] = s*(1.f/196.f);
  }
}

// ---------- chan_inter on x1 mean -> sigmoid gate CMAP ----------
__global__ __launch_bounds__(256) void k_cinter(const float* __restrict__ X1S,
    const float* __restrict__ ci1w, const float* __restrict__ ci1b,
    const float* __restrict__ bng, const float* __restrict__ bnb,
    const float* __restrict__ ci2w, const float* __restrict__ ci2b, float* __restrict__ CMAP){
  int b = blockIdx.x, c = threadIdx.x;
  __shared__ float p[256], tt[16];
  p[c] = X1S[b*256 + c];
  __syncthreads();
  if (c < 16){
    float a = ci1b[c];
    #pragma unroll 4
    for (int k = 0; k < 256; ++k) a = fmaf(ci1w[(c*256+k)*25 + 12], p[k], a);  // 5x5 center
    const float invs = 0.9999950000375f;   // 1/sqrt(1+1e-5)
    tt[c] = fmaxf(fmaf(bng[c]*invs, a, bnb[c]), 0.f);
  }
  __syncthreads();
  float a = ci2b[c];
  #pragma unroll
  for (int k = 0; k < 16; ++k) a = fmaf(ci2w[(c*16+k)*25 + 12], tt[k], a);
  CMAP[b*256 + c] = sigmoidf_(a);
}

// ---------- agent_v via fp16 MFMA (round-9: gate fused into pass-0 V staging) ----------
__global__ __launch_bounds__(256) void k_agentv(const float* __restrict__ Y, const float* __restrict__ V5,
    const float* __restrict__ CHG, const float* __restrict__ MK,
    const float* __restrict__ AT, const float* __restrict__ ATK,
    const float* __restrict__ PBT, float* __restrict__ AGV){
  int b = blockIdx.x >> 3, h = blockIdx.x & 7;
  __shared__ __align__(16) ushort_t ST[64*232];   // exp-scores, [a][n pad 232]
  __shared__ __align__(16) ushort_t R[8704];      // staging region (17408 B)
  __shared__ float psum[4*64];
  __shared__ float inv0s[64], inv1s[64];
  __shared__ float mks[196];
  __shared__ float chgs[32];
  int tid = threadIdx.x, wv = tid >> 6, lane = tid & 63;
  int mrow = lane & 15, quad = lane >> 4;
  int sw8 = ((quad ^ ((mrow >> 1) & 3)) << 3);    // read-side chunk swizzle (rows = 16*t + mrow)
  const float* yb = Y + (size_t)b*YSTR;
  ushort_t* Kh = R;            // [208][32] fp16 rows (K or Q), chunk-swizzled
  ushort_t* Ah = R + 6656;     // [64][32] fp16 rows (AT or ATK), chunk-swizzled
  ushort_t* Vt = R;            // [32][232] fp16 rows (V1 or V)
  f32x4 out0[2], out1[2];

  // ---- one-time: gate tables + zero fills of ST cols 208..223 ----
  if (tid < 196) mks[tid] = MK[(size_t)b*196 + tid];
  if (tid >= 224) chgs[tid - 224] = CHG[(size_t)b*256 + h*32 + (tid - 224)];
  for (int t = tid; t < 512; t += 256){      // 64 rows x 16 cols /2 per uint
    int a = t >> 3, c2 = 208 + ((t & 7) << 1);
    *(uint_t*)&ST[a*232 + c2] = 0;
  }

  #pragma unroll 1
  for (int pass = 0; pass < 2; ++pass){
    // ---- stage rows (K|Q into Kh; AT|ATK into Ah), zero pads ----
    for (int t = tid; t < 192; t += 256) ((uint_t*)Kh)[3136 + t] = 0;   // rows 196-207
    for (int t = tid; t < 240; t += 256) ((uint_t*)Ah)[784 + t] = 0;    // rows 49-63
    {
      const float* rsrc = yb + (pass ? QOFF : 0) + h*32;
      for (int t = tid; t < 3136; t += 256){
        int n = t >> 4, w = t & 15;
        const float2 v = *(const float2*)(rsrc + (size_t)n*256 + (w << 1));
        int ws = (((w >> 2) ^ ((n >> 1) & 3)) << 2) | (w & 3);
        ((uint_t*)Kh)[n*16 + ws] = (uint_t)f2h(v.x) | ((uint_t)f2h(v.y) << 16);
      }
      const float* asrc = (pass ? ATK : AT) + (size_t)b*49*256 + h*32;
      for (int t = tid; t < 784; t += 256){
        int a = t >> 4, w = t & 15;
        const float2 v = *(const float2*)(asrc + (size_t)a*256 + (w << 1));
        int ws = (((w >> 2) ^ ((a >> 1) & 3)) << 2) | (w & 3);
        ((uint_t*)Ah)[a*16 + ws] = (uint_t)f2h(v.x) | ((uint_t)f2h(v.y) << 16);
      }
    }
    __syncthreads();
    // ---- logits: ntile = wv; 13 mtiles; exp(+pb) -> ST[a][n] ----
    {
      float lscl = pass ? 0.03125f : SCL;
      int ag = wv*16 + mrow;                 // agent (C col)
      half8 bfr = *(const half8*)&Ah[ag*32 + sw8];
      #pragma unroll 1
      for (int mt = 0; mt < 13; ++mt){
        half8 afr = *(const half8*)&Kh[(mt*16 + mrow)*32 + sw8];
        f32x4 c = (f32x4){0.f,0.f,0.f,0.f};
        c = __builtin_amdgcn_mfma_f32_16x16x32_f16(afr, bfr, c, 0, 0, 0);
        int n0 = mt*16 + quad*4;
        short4v pk;
        #pragma unroll
        for (int r = 0; r < 4; ++r){
          int n = n0 + r;
          float pb = PBT[((size_t)h*196 + n)*49 + ag];
          float e = (n < 196) ? __expf(fmaf(c[r], lscl, pb)) : 0.f;
          pk[r] = (short)f2h(e);
        }
        *(short4v*)&ST[ag*232 + n0] = pk;
      }
    }
    __syncthreads();
    // ---- denominators + stage V ----
    {
      int a = tid >> 2, q = tid & 3;
      float s = 0.f;
      #pragma unroll
      for (int u = 0; u < 7; ++u){
        short8 v8 = *(const short8*)&ST[a*232 + q*56 + u*8];
        #pragma unroll
        for (int e = 0; e < 8; ++e) s += h2f((ushort_t)v8[e]);
      }
      psum[q*64 + a] = s;
    }
    if (pass == 0){
      const float* vsrc = V5 + (size_t)b*50176 + h*32*196;   // [d][196] raw v5
      for (int t = tid; t < 3136; t += 256){
        int d = t / 98, np = t - (t/98)*98;
        const float2 v = *(const float2*)(vsrc + (size_t)d*196 + 2*np);
        float g = chgs[d];
        float a0 = (g*v.x)*mks[2*np];
        float a1 = (g*v.y)*mks[2*np + 1];
        *(uint_t*)&Vt[d*232 + 2*np] = (uint_t)f2h(a0) | ((uint_t)f2h(a1) << 16);
      }
    } else {
      const float* vsrc = yb + VOFF + h*32;                  // [n][256] flat view
      for (int t = tid; t < 3136; t += 256){
        int np = t >> 4, dp = t & 15;
        const float2 v = *(const float2*)(vsrc + (size_t)np*256 + (dp << 1));
        Vt[(2*dp)*232 + np]     = f2h(v.x);
        Vt[(2*dp + 1)*232 + np] = f2h(v.y);
      }
    }
    for (int t = tid; t < 448; t += 256){    // zero V cols 196..223
      int d = t / 14, c2 = 196 + 2*(t - (t/14)*14);
      *(uint_t*)&Vt[d*232 + c2] = 0;
    }
    __syncthreads();
    // ---- PV: mtile = wv (a rows); ntile 0..1 (d cols); 7 k-steps ----
    {
      f32x4* outp = pass ? out1 : out0;
      #pragma unroll
      for (int nt = 0; nt < 2; ++nt){
        f32x4 c = (f32x4){0.f,0.f,0.f,0.f};
        #pragma unroll
        for (int ks = 0; ks < 7; ++ks){
          half8 afr = *(const half8*)&ST[(wv*16 + mrow)*232 + ks*32 + quad*8];
          half8 bfr = *(const half8*)&Vt[(nt*16 + mrow)*232 + ks*32 + quad*8];
          c = __builtin_amdgcn_mfma_f32_16x16x32_f16(afr, bfr, c, 0, 0, 0);
        }
        outp[nt] = c;
      }
      if (tid < 64){
        float s = psum[tid] + psum[64+tid] + psum[128+tid] + psum[192+tid];
        float* invp = pass ? inv1s : inv0s;
        invp[tid] = 1.f / s;
      }
    }
    __syncthreads();   // ST/Vt free for next pass; inv visible
  }
  // ---- epilogue: combine + scatter ----
  #pragma unroll
  for (int nt = 0; nt < 2; ++nt){
    int d = nt*16 + mrow;
    #pragma unroll
    for (int r = 0; r < 4; ++r){
      int a = wv*16 + quad*4 + r;
      if (a < 49)
        AGV[(((size_t)(b*8 + h)*49) + a)*32 + d] = out0[nt][r]*inv0s[a] + out1[nt][r]*inv1s[a];
    }
  }
}

// ---------- xo1 via fp16 MFMA ----------
__global__ __launch_bounds__(256) void k_xo1(const float* __restrict__ Y,
    const float* __restrict__ AT, const float* __restrict__ ATK,
    const float* __restrict__ AB, const float* __restrict__ AGV, float* __restrict__ XO){
  int b = blockIdx.x >> 3, h = blockIdx.x & 7;
  __shared__ __align__(16) ushort_t ST[208*72];   // exp-scores [n][a pad 72]
  __shared__ __align__(16) ushort_t Kh[208*32];   // Q or K rows fp16, chunk-swizzled
  __shared__ __align__(16) ushort_t Ah[64*32];    // AT or ATK rows fp16, chunk-swizzled
  __shared__ __align__(16) ushort_t AGVt[32*64];  // AGV^T [d][a], chunk-swizzled
  __shared__ float invs[208];
  int tid = threadIdx.x, wv = tid >> 6, lane = tid & 63;
  int mrow = lane & 15, quad = lane >> 4;
  int sw8 = ((quad ^ ((mrow >> 1) & 3)) << 3);    // 64B-row read swizzle
  const float* yb = Y + (size_t)b*YSTR;
  f32x4 acc[4][2];
  #pragma unroll
  for (int i = 0; i < 4; ++i){
    acc[i][0] = (f32x4){0.f,0.f,0.f,0.f};
    acc[i][1] = (f32x4){0.f,0.f,0.f,0.f};
  }

  for (int t = tid; t < 1664; t += 256){
    int rw = t >> 3, c2 = 48 + ((t & 7) << 1);
    *(uint_t*)&ST[rw*72 + c2] = 0;
  }
  {
    const float* agvb = AGV + (size_t)(b*8 + h)*49*32;
    for (int t = tid; t < 2048; t += 256){
      int d = t >> 6, a = t & 63;
      int as = ((((a >> 3) ^ (d & 7)) & 7) << 3) | (a & 7);
      AGVt[d*64 + as] = (a < 49) ? f2h(agvb[a*32 + d]) : (ushort_t)0;
    }
  }

  #pragma unroll 1
  for (int pass = 0; pass < 2; ++pass){
    {
      const float* rsrc = yb + (pass ? 0 : QOFF) + h*32;
      for (int t = tid; t < 3136; t += 256){
        int n = t >> 4, w = t & 15;
        const float2 v = *(const float2*)(rsrc + (size_t)n*256 + (w << 1));
        int ws = (((w >> 2) ^ ((n >> 1) & 3)) << 2) | (w & 3);
        ((uint_t*)Kh)[n*16 + ws] = (uint_t)f2h(v.x) | ((uint_t)f2h(v.y) << 16);
      }
      const float* asrc = (pass ? ATK : AT) + (size_t)b*49*256 + h*32;
      for (int t = tid; t < 784; t += 256){
        int a = t >> 4, w = t & 15;
        const float2 v = *(const float2*)(asrc + (size_t)a*256 + (w << 1));
        int ws = (((w >> 2) ^ ((a >> 1) & 3)) << 2) | (w & 3);
        ((uint_t*)Ah)[a*16 + ws] = (uint_t)f2h(v.x) | ((uint_t)f2h(v.y) << 16);
      }
    }
    __syncthreads();
    {
      float lscl = pass ? SCL : 0.03125f;
      int ag = wv*16 + mrow;
      half8 bfr = *(const half8*)&Ah[ag*32 + sw8];
      #pragma unroll 1
      for (int mt = 0; mt < 13; ++mt){
        half8 afr = *(const half8*)&Kh[(mt*16 + mrow)*32 + sw8];
        f32x4 c = (f32x4){0.f,0.f,0.f,0.f};
        c = __builtin_amdgcn_mfma_f32_16x16x32_f16(afr, bfr, c, 0, 0, 0);
        #pragma unroll
        for (int r = 0; r < 4; ++r){
          int n = mt*16 + quad*4 + r;
          if (n < 196 && ag < 49){
            float e = __expf(fmaf(c[r], lscl, AB[((size_t)h*196 + n)*49 + ag]));
            ST[n*72 + ag] = f2h(e);
          }
        }
      }
    }
    __syncthreads();
    if (tid < 196){
      float s = 0.f;
      #pragma unroll
      for (int u = 0; u < 7; ++u){
        short8 v8 = *(const short8*)&ST[tid*72 + u*8];
        #pragma unroll
        for (int e = 0; e < 8; ++e) s += h2f((ushort_t)v8[e]);
      }
      invs[tid] = 1.f / s;
    }
    __syncthreads();
    {
      int i = 0;
      #pragma unroll 1
      for (int mt = wv; mt < 13; mt += 4, ++i){
        #pragma unroll
        for (int nt = 0; nt < 2; ++nt){
          f32x4 c = (f32x4){0.f,0.f,0.f,0.f};
          #pragma unroll
          for (int ks = 0; ks < 2; ++ks){
            half8 afr = *(const half8*)&ST[(mt*16 + mrow)*72 + ks*32 + quad*8];
            half8 bfr = *(const half8*)&AGVt[(nt*16 + mrow)*64 + ((((ks*4 + quad) ^ (mrow & 7)) & 7) << 3)];
            c = __builtin_amdgcn_mfma_f32_16x16x32_f16(afr, bfr, c, 0, 0, 0);
          }
          #pragma unroll
          for (int r = 0; r < 4; ++r){
            int n = mt*16 + quad*4 + r;
            if (n < 196) acc[i][nt][r] = fmaf(c[r], invs[n], acc[i][nt][r]);
          }
        }
      }
    }
    __syncthreads();
  }
  {
    int i = 0;
    #pragma unroll 1
    for (int mt = wv; mt < 13; mt += 4, ++i){
      #pragma unroll
      for (int nt = 0; nt < 2; ++nt){
        #pragma unroll
        for (int r = 0; r < 4; ++r){
          int n = mt*16 + quad*4 + r;
          if (n < 196)
            XO[((size_t)b*196 + n)*256 + h*32 + nt*16 + mrow] = acc[i][nt][r];
        }
      }
    }
  }
}

// ---------- fused depthwise conv: dwc(conv_x2 + qc), bias 2*dwc_b, accumulated into XO ----------
__global__ __launch_bounds__(256) void k_dwc(const float* __restrict__ Y, const float* __restrict__ CMAP,
    const float* __restrict__ dw, const float* __restrict__ db, float* __restrict__ XO){
  int b = blockIdx.x >> 3, cg = blockIdx.x & 7;
  int c0 = cg*32;
  __shared__ __align__(16) float pl[32*360];
  int tid = threadIdx.x;
  for (int t = tid; t < 32*360; t += 256) pl[t] = 0.f;
  __syncthreads();
  const float* yq = Y + (size_t)b*YSTR + QOFF;
  for (int t = tid; t < 32*196; t += 256){
    int cl = t & 31, s = t >> 5;
    int c = c0 + cl;
    int G = s*256 + c;                 // head-major flat index for conv_x2's scramble
    int hh = G / 6272;
    int rem = G - hh*6272;
    int n = rem >> 5, d = rem & 31;
    float cx2 = CMAP[b*256 + c] * yq[n*256 + hh*32 + d];   // sigmoid(cmap)*qs
    float qc  = yq[G];                                     // qc collapses to identity gather
    float v = SCL*(cx2 + qc);
    int i = s/14, j = s - i*14;
    pl[cl*360 + (i+2)*20 + j + 2] = v;
  }
  __syncthreads();
  for (int t = tid; t < 32*14; t += 256){
    int cl = t/14, r = t - cl*14;
    int c = c0 + cl;
    float w25[25];
    #pragma unroll
    for (int u = 0; u < 25; ++u) w25[u] = dw[c*25 + u];
    float acc[14];
    float b2 = 2.f*db[c];
    #pragma unroll
    for (int j = 0; j < 14; ++j) acc[j] = b2;
    conv5x5_row(&pl[cl*360], r, w25, acc);
    float* dst = XO + ((size_t)b*196 + r*14)*256 + c;
    #pragma unroll
    for (int j = 0; j < 14; ++j) dst[j*256] += acc[j];
  }
}

// ---------- final projection: out = XO @ proj_w^T + proj_b ----------
__global__ __launch_bounds__(256) void k_proj(const float* __restrict__ XO, const float* __restrict__ WT,
    const float* __restrict__ pbias, float* __restrict__ OUT){
  int bb = blockIdx.x / 7, nt = blockIdx.x % 7;
  int n0 = nt*28;
  int c = threadIdx.x;
  const float* xb = XO + ((size_t)bb*196 + n0)*256;
  float acc[28];
  #pragma unroll
  for (int r = 0; r < 28; ++r) acc[r] = 0.f;
  for (int k = 0; k < 256; k += 4){
    float w0 = WT[(k+0)*256 + c];
    float w1 = WT[(k+1)*256 + c];
    float w2 = WT[(k+2)*256 + c];
    float w3 = WT[(k+3)*256 + c];
    #pragma unroll
    for (int r = 0; r < 28; ++r){
      float4 xv = *(const float4*)(xb + r*256 + k);   // uniform address -> scalar/L1 path
      acc[r] = fmaf(xv.x, w0, fmaf(xv.y, w1, fmaf(xv.z, w2, fmaf(xv.w, w3, acc[r]))));
    }
  }
  float bv = pbias[c];
  float* dst = OUT + ((size_t)bb*196 + n0)*256 + c;
  #pragma unroll
  for (int r = 0; r < 28; ++r) dst[r*256] = acc[r] + bv;
}

extern "C" void kernel_launch(void* const* d_in, const int* in_sizes, int n_in,
                              void* d_out, int out_size, void* d_ws, size_t ws_size,
                              hipStream_t stream){
  (void)in_sizes; (void)n_in; (void)out_size; (void)ws_size;
  const float* x       = (const float*)d_in[0];
  const float* lka_w   = (const float*)d_in[3];
  const float* lka_b   = (const float*)d_in[4];
  const float* conv5_w = (const float*)d_in[5];
  const float* conv5_b = (const float*)d_in[6];
  const float* caa1_w  = (const float*)d_in[7];
  const float* caa1_b  = (const float*)d_in[8];
  const float* caa2_w  = (const float*)d_in[9];
  const float* caa2_b  = (const float*)d_in[10];
  const float* cam1_w  = (const float*)d_in[11];
  const float* cam1_b  = (const float*)d_in[12];
  const float* cam2_w  = (const float*)d_in[13];
  const float* cam2_b  = (const float*)d_in[14];
  const float* sa_w    = (const float*)d_in[15];
  const float* sa_b    = (const float*)d_in[16];
  const float* ci1_w   = (const float*)d_in[17];
  const float* ci1_b   = (const float*)d_in[18];
  const float* bn_g    = (const float*)d_in[19];
  const float* bn_b    = (const float*)d_in[20];
  const float* ci2_w   = (const float*)d_in[21];
  const float* ci2_b   = (const float*)d_in[22];
  const float* rpbt    = (const float*)d_in[23];
  const float* an_bias = (const float*)d_in[24];
  const float* na_bias = (const float*)d_in[25];
  const float* ah_bias = (const float*)d_in[26];
  const float* aw_bias = (const float*)d_in[27];
  const float* ha_bias = (const float*)d_in[28];
  const float* wa_bias = (const float*)d_in[29];
  const float* dwc_w   = (const float*)d_in[30];
  const float* dwc_b   = (const float*)d_in[31];
  const float* proj_w  = (const float*)d_in[32];
  const float* proj_b  = (const float*)d_in[33];
  float* out = (float*)d_out;
  float* ws = (float*)d_ws;

  float* Y    = ws + WS_Y;
  float* V5   = ws + WS_V5;
  float* AT   = ws + WS_AT;
  float* ATK  = ws + WS_ATK;
  float* CHG  = ws + WS_CHG;   // avg, then chg in-place
  float* CMAP = ws + WS_CMAP;
  float* PBT  = ws + WS_PBT;
  float* AB   = ws + WS_AB;
  float* X1S  = ws + WS_X1S;
  float* AGV  = ws + WS_AGV;
  float* XO   = ws + WS_XO;
  float* WT   = ws + WS_WT;
  ushort_t* Wh = (ushort_t*)(ws + WS_CWT);
  float* MXp  = ws + WS_MX;
  float* MKp  = ws + WS_MK;

  k_pbab <<<602, 256, 0, stream>>>(an_bias, ah_bias, aw_bias, na_bias, ha_bias, wa_bias, PBT, AB);
  k_wprep<<<1056, 256, 0, stream>>>(conv5_w, Wh, proj_w, WT);
  k_lka  <<<1024, 256, 0, stream>>>(x, lka_w, lka_b, Y);
  k_conv5<<<512, 256, 0, stream>>>(Y, Wh, conv5_b, V5);
  k_pool <<<256, 256, 0, stream>>>(Y, AT, ATK);
  k_cbam_a2<<<1024, 256, 0, stream>>>(V5, CHG, MXp);
  k_cbam_b2<<<128, 512, 0, stream>>>(V5, CHG, MXp, caa1_w, caa1_b, caa2_w, caa2_b,
                                     cam1_w, cam1_b, cam2_w, cam2_b, sa_w, sa_b, MKp);
  k_attn3<<<1024, 512, 0, stream>>>(Y, rpbt, X1S);
  k_cinter<<<128, 256, 0, stream>>>(X1S, ci1_w, ci1_b, bn_g, bn_b, ci2_w, ci2_b, CMAP);
  k_agentv<<<1024, 256, 0, stream>>>(Y, V5, CHG, MKp, AT, ATK, PBT, AGV);
  k_xo1  <<<1024, 256, 0, stream>>>(Y, AT, ATK, AB, AGV, XO);
  k_dwc  <<<1024, 256, 0, stream>>>(Y, CMAP, dwc_w, dwc_b, XO);
  k_proj <<<896, 256, 0, stream>>>(XO, WT, proj_b, out);
}